// Round 1
// baseline (7242.563 us; speedup 1.0000x reference)
//
#include <hip/hip_runtime.h>
#include <hip/hip_bf16.h>

// Problem constants
#define NN   10000   // nodes
#define SS   4       // walks per node
#define BB   40000   // S*N sequences
#define HH   64      // hidden
#define LLEN 8       // walk length
#define DD   193     // final GRU input dim (64 hw + 128 y + 1 deg)
#define G3   192     // 3*H gates

// ws layout (bytes)
#define OFF_DMAX 0
#define OFF_DEGN 1024
#define OFF_A    65536                      // 10000*192*4 = 7,680,000 B
#define OFF_YF   (8u*1024u*1024u)           // 40000*8*64*2 = 40,960,000 B
#define OFF_YB   (52u*1024u*1024u)          // 40,960,000 B  (end ~91.1 MiB)

__device__ __forceinline__ float sigm(float x) { return 1.0f / (1.0f + __expf(-x)); }
__device__ __forceinline__ float tanh_(float x) {
    float e = __expf(-2.0f * fabsf(x));
    float t = (1.0f - e) / (1.0f + e);
    return x >= 0.0f ? t : -t;
}

__global__ void k_zero(int* dmax) {
    if (threadIdx.x == 0 && blockIdx.x == 0) *dmax = 0;
}

// max over gathered in-degrees (deg.max() in reference is over the gathered array)
__global__ void k_degmax(const int* __restrict__ walks, const int* __restrict__ indeg,
                         int* __restrict__ dmax) {
    int i = blockIdx.x * blockDim.x + threadIdx.x;
    int d = 0;
    if (i < SS * NN * LLEN) d = indeg[walks[i]];
    #pragma unroll
    for (int off = 32; off > 0; off >>= 1) d = max(d, __shfl_xor(d, off));
    if ((threadIdx.x & 63) == 0 && d > 0) atomicMax(dmax, d);
}

__global__ void k_degn(const int* __restrict__ indeg, const int* __restrict__ dmax,
                       float* __restrict__ degn) {
    int n = blockIdx.x * blockDim.x + threadIdx.x;
    if (n < NN) degn[n] = (float)indeg[n] / (float)(*dmax);
}

// A[n][g] = bih[g] + sum_k h[n][k] * Wih[g][k]   (cols 0..63 of Wih)
__global__ __launch_bounds__(192) void k_A(const float* __restrict__ h,
                                           const float* __restrict__ Wih,
                                           const float* __restrict__ bih,
                                           float* __restrict__ A) {
    int g = threadIdx.x;  // 0..191
    float w[64];
    #pragma unroll
    for (int k = 0; k < 64; ++k) w[k] = Wih[g * DD + k];
    float bg = bih[g];
    __shared__ float hs[64];
    int n0 = blockIdx.x * 32;
    for (int j = 0; j < 32; ++j) {
        int n = n0 + j;
        if (n >= NN) break;            // uniform per block
        __syncthreads();
        if (g < 64) hs[g] = h[n * 64 + g];
        __syncthreads();
        float acc = bg;
        #pragma unroll
        for (int k = 0; k < 64; ++k) acc += w[k] * hs[k];
        A[n * G3 + g] = acc;
    }
}

// One thread = one sequence. h state in VGPRs (static k-index); runtime-indexed
// h[i] update goes through per-lane LDS column hb[i][tid] (2-way bank, free).
// Weights read at uniform addresses -> scalar loads (K$/L2 broadcast).
__global__ __launch_bounds__(64, 1) void k_main(
    const int* __restrict__ walks, const float* __restrict__ degn,
    const float* __restrict__ A,
    const float* __restrict__ Wf, const float* __restrict__ Uf,
    const float* __restrict__ bif, const float* __restrict__ bhf,
    const float* __restrict__ Wb, const float* __restrict__ Ub,
    const float* __restrict__ bib, const float* __restrict__ bhb,
    const float* __restrict__ W, const float* __restrict__ U,
    const float* __restrict__ bh,
    __hip_bfloat16* __restrict__ yfw, __hip_bfloat16* __restrict__ ybw,
    float* __restrict__ out) {
    __shared__ float hb[64][64];
    const int tid = threadIdx.x;
    const int b = blockIdx.x * 64 + tid;
    const int* wk = walks + b * LLEN;

    float h[64];
    #pragma unroll
    for (int k = 0; k < 64; ++k) { h[k] = 0.0f; hb[k][tid] = 0.0f; }

    // ---------------- forward GRU over reversed walk ----------------
    for (int t = 0; t < LLEN; ++t) {
        int p = LLEN - 1 - t;       // original index of reversed position t
        int wp = wk[p];
        int u = 7;
        #pragma unroll
        for (int j = 7; j >= 0; --j) if (wk[j] == wp) u = j;   // first occurrence
        float uf = (float)u * 0.7853981633974483f;             // u * 2pi/8
        float si = __sinf(uf), ci = __cosf(uf);
        for (int i = 0; i < 64; ++i) {
            float xr = bif[i]       + Wf[i * 2] * si         + Wf[i * 2 + 1] * ci;
            float xz = bif[64 + i]  + Wf[(64 + i) * 2] * si  + Wf[(64 + i) * 2 + 1] * ci;
            float xn = bif[128 + i] + Wf[(128 + i) * 2] * si + Wf[(128 + i) * 2 + 1] * ci;
            float hr = bhf[i], hz = bhf[64 + i], hn = bhf[128 + i];
            #pragma unroll
            for (int k = 0; k < 64; ++k) {
                float hk = h[k];
                hr += Uf[i * 64 + k] * hk;
                hz += Uf[(64 + i) * 64 + k] * hk;
                hn += Uf[(128 + i) * 64 + k] * hk;
            }
            float r = sigm(xr + hr), z = sigm(xz + hz);
            float n = tanh_(xn + r * hn);
            float hold = hb[i][tid];
            hb[i][tid] = (1.0f - z) * n + z * hold;
        }
        #pragma unroll
        for (int k = 0; k < 64; ++k) {
            float v = hb[k][tid];
            h[k] = v;
            yfw[(t * 64 + k) * BB + b] = __float2bfloat16(v);
        }
    }
    float hf[64];
    #pragma unroll
    for (int k = 0; k < 64; ++k) hf[k] = h[k];

    // ---------------- backward GRU (reverse scan) ----------------
    #pragma unroll
    for (int k = 0; k < 64; ++k) { h[k] = 0.0f; hb[k][tid] = 0.0f; }
    for (int tt = LLEN - 1; tt >= 0; --tt) {
        int p = LLEN - 1 - tt;
        int wp = wk[p];
        int u = 7;
        #pragma unroll
        for (int j = 7; j >= 0; --j) if (wk[j] == wp) u = j;
        float uf = (float)u * 0.7853981633974483f;
        float si = __sinf(uf), ci = __cosf(uf);
        for (int i = 0; i < 64; ++i) {
            float xr = bib[i]       + Wb[i * 2] * si         + Wb[i * 2 + 1] * ci;
            float xz = bib[64 + i]  + Wb[(64 + i) * 2] * si  + Wb[(64 + i) * 2 + 1] * ci;
            float xn = bib[128 + i] + Wb[(128 + i) * 2] * si + Wb[(128 + i) * 2 + 1] * ci;
            float hr = bhb[i], hz = bhb[64 + i], hn = bhb[128 + i];
            #pragma unroll
            for (int k = 0; k < 64; ++k) {
                float hk = h[k];
                hr += Ub[i * 64 + k] * hk;
                hz += Ub[(64 + i) * 64 + k] * hk;
                hn += Ub[(128 + i) * 64 + k] * hk;
            }
            float r = sigm(xr + hr), z = sigm(xz + hz);
            float n = tanh_(xn + r * hn);
            float hold = hb[i][tid];
            hb[i][tid] = (1.0f - z) * n + z * hold;
        }
        #pragma unroll
        for (int k = 0; k < 64; ++k) {
            float v = hb[k][tid];
            h[k] = v;
            ybw[(tt * 64 + k) * BB + b] = __float2bfloat16(v);
        }
    }

    // h_walk = 0.5*(hf + hb)
    #pragma unroll
    for (int k = 0; k < 64; ++k) {
        float hw_ = 0.5f * (hf[k] + h[k]);
        h[k] = hw_;
        hb[k][tid] = hw_;
    }

    // ---------------- final GRU ----------------
    for (int t = 0; t < LLEN; ++t) {
        int p = LLEN - 1 - t;
        int wp = wk[p];
        float dg = degn[wp];
        const float* Ar = A + wp * G3;
        float yf[64], yb[64];
        #pragma unroll
        for (int k = 0; k < 64; ++k) {
            yf[k] = __bfloat162float(yfw[(t * 64 + k) * BB + b]);
            yb[k] = __bfloat162float(ybw[(t * 64 + k) * BB + b]);
        }
        for (int i = 0; i < 64; ++i) {
            float xr = Ar[i]       + dg * W[i * DD + 192];
            float xz = Ar[64 + i]  + dg * W[(64 + i) * DD + 192];
            float xn = Ar[128 + i] + dg * W[(128 + i) * DD + 192];
            float hr = bh[i], hz = bh[64 + i], hn = bh[128 + i];
            #pragma unroll
            for (int k = 0; k < 64; ++k) {
                float hk = h[k];
                hr += U[i * 64 + k] * hk;
                hz += U[(64 + i) * 64 + k] * hk;
                hn += U[(128 + i) * 64 + k] * hk;
                xr += W[i * DD + 64 + k] * yf[k]         + W[i * DD + 128 + k] * yb[k];
                xz += W[(64 + i) * DD + 64 + k] * yf[k]  + W[(64 + i) * DD + 128 + k] * yb[k];
                xn += W[(128 + i) * DD + 64 + k] * yf[k] + W[(128 + i) * DD + 128 + k] * yb[k];
            }
            float r = sigm(xr + hr), z = sigm(xz + hz);
            float n = tanh_(xn + r * hn);
            float hold = hb[i][tid];
            hb[i][tid] = (1.0f - z) * n + z * hold;
        }
        #pragma unroll
        for (int k = 0; k < 64; ++k) h[k] = hb[k][tid];
    }

    #pragma unroll
    for (int k = 0; k < 64; ++k) out[b * 64 + k] = h[k];
}

extern "C" void kernel_launch(void* const* d_in, const int* in_sizes, int n_in,
                              void* d_out, int out_size, void* d_ws, size_t ws_size,
                              hipStream_t stream) {
    const float* h     = (const float*)d_in[0];
    const int*   walks = (const int*)d_in[1];
    const int*   indeg = (const int*)d_in[2];
    const float* Wf    = (const float*)d_in[3];
    const float* Uf    = (const float*)d_in[4];
    const float* bif   = (const float*)d_in[5];
    const float* bhf   = (const float*)d_in[6];
    const float* Wb    = (const float*)d_in[7];
    const float* Ub    = (const float*)d_in[8];
    const float* bib   = (const float*)d_in[9];
    const float* bhb   = (const float*)d_in[10];
    const float* W     = (const float*)d_in[11];
    const float* U     = (const float*)d_in[12];
    const float* bi    = (const float*)d_in[13];
    const float* bh    = (const float*)d_in[14];
    float* out = (float*)d_out;

    char* ws = (char*)d_ws;
    int*   dmax = (int*)(ws + OFF_DMAX);
    float* degn = (float*)(ws + OFF_DEGN);
    float* A    = (float*)(ws + OFF_A);
    __hip_bfloat16* yfw = (__hip_bfloat16*)(ws + OFF_YF);
    __hip_bfloat16* ybw = (__hip_bfloat16*)(ws + OFF_YB);

    k_zero<<<1, 64, 0, stream>>>(dmax);
    k_degmax<<<(SS * NN * LLEN + 255) / 256, 256, 0, stream>>>(walks, indeg, dmax);
    k_degn<<<(NN + 255) / 256, 256, 0, stream>>>(indeg, dmax, degn);
    k_A<<<(NN + 31) / 32, 192, 0, stream>>>(h, W, bi, A);
    k_main<<<BB / 64, 64, 0, stream>>>(walks, degn, A,
                                       Wf, Uf, bif, bhf,
                                       Wb, Ub, bib, bhb,
                                       W, U, bh,
                                       yfw, ybw, out);
}

// Round 5
// 383.466 us; speedup vs baseline: 18.8871x; 18.8871x over previous
//
#include <hip/hip_runtime.h>
#include <hip/hip_bf16.h>

#define NN   10000
#define SS   4
#define BB   40000
#define LLEN 8
#define DD   193
#define G3   192

typedef __attribute__((ext_vector_type(8))) short bf16x8;
typedef __attribute__((ext_vector_type(4))) short short4v;
typedef __attribute__((ext_vector_type(4))) float f32x4;

// ws layout (bytes)
#define OFF_DMAX 0
#define OFF_DEGN 1024
#define OFF_A    65536                 // 10000*192*4 = 7.68 MB
#define OFF_YF   (8ull*1024*1024)      // [t][kb][BB][4] bf16 = 40.96 MB
#define OFF_YB   (49ull*1024*1024)     // 40.96 MB
#define OFF_HFB  (90ull*1024*1024)     // [dir][BB][64] bf16 = 10.24 MB (end ~97.8 MiB)

__device__ __forceinline__ float sigm(float x){ return 1.0f/(1.0f+__expf(-x)); }
__device__ __forceinline__ float tanh_(float x){
  float e = __expf(-2.0f*fabsf(x));
  float t = (1.0f-e)/(1.0f+e);
  return x>=0.0f ? t : -t;
}
__device__ __forceinline__ short f2b(float f){            // RNE float->bf16
  unsigned u = __builtin_bit_cast(unsigned, f);
  u = u + 0x7FFFu + ((u>>16)&1u);
  return (short)(u>>16);
}
__device__ __forceinline__ float b2f(short s){
  unsigned u = ((unsigned)(unsigned short)s)<<16;
  return __builtin_bit_cast(float, u);
}

__global__ void k_zero(int* dmax){
  if (threadIdx.x==0 && blockIdx.x==0) *dmax = 0;
}

__global__ void k_degmax(const int* __restrict__ walks, const int* __restrict__ indeg,
                         int* __restrict__ dmax){
  int i = blockIdx.x*blockDim.x + threadIdx.x;
  int d = 0;
  if (i < SS*NN*LLEN) d = indeg[walks[i]];
  #pragma unroll
  for (int off=32; off>0; off>>=1) d = max(d, __shfl_xor(d, off));
  if ((threadIdx.x&63)==0 && d>0) atomicMax(dmax, d);
}

__global__ void k_degn(const int* __restrict__ indeg, const int* __restrict__ dmax,
                       float* __restrict__ degn){
  int n = blockIdx.x*blockDim.x + threadIdx.x;
  if (n < NN) degn[n] = (float)indeg[n] / (float)(*dmax);
}

// A[n][g] = bih[g] + sum_k h[n][k]*Wih[g][k]  (cols 0..63)
__global__ __launch_bounds__(192) void k_A(const float* __restrict__ h,
                                           const float* __restrict__ Wih,
                                           const float* __restrict__ bih,
                                           float* __restrict__ A){
  int g = threadIdx.x;
  float w[64];
  #pragma unroll
  for (int k=0;k<64;++k) w[k] = Wih[g*DD + k];
  float bg = bih[g];
  __shared__ float hs[64];
  int n0 = blockIdx.x*32;
  for (int j=0;j<32;++j){
    int n = n0 + j;
    if (n >= NN) break;
    __syncthreads();
    if (g < 64) hs[g] = h[n*64+g];
    __syncthreads();
    float acc = bg;
    #pragma unroll
    for (int k=0;k<64;++k) acc += w[k]*hs[k];
    A[n*G3 + g] = acc;
  }
}

// ---------------- fwd/bwd GRU, MFMA, 4 waves x 16 seqs ----------------
// D[gate][seq]: per wave, 12 gate-tiles of 16. Lane: seq = sBase+(lane&15),
// owns channels i = q*16 + 4*(lane>>4) + r.  No intra-loop barriers (h rows wave-private).
__global__ __launch_bounds__(256,3) void k_fb(
    const int* __restrict__ walks,
    const float* __restrict__ Wih_f, const float* __restrict__ Whh_f,
    const float* __restrict__ bih_f, const float* __restrict__ bhh_f,
    const float* __restrict__ Wih_b, const float* __restrict__ Whh_b,
    const float* __restrict__ bih_b, const float* __restrict__ bhh_b,
    short* __restrict__ yf_out, short* __restrict__ yb_out,
    short* __restrict__ hfb)
{
  const int dir = blockIdx.y;
  const float* Wih = dir ? Wih_b : Wih_f;
  const float* Whh = dir ? Whh_b : Whh_f;
  const float* bih = dir ? bih_b : bih_f;
  const float* bhh = dir ? bhh_b : bhh_f;
  short* yout = dir ? yb_out : yf_out;

  __shared__ __align__(16) short Wlds[192*64];   // swizzled [g][k]
  __shared__ __align__(16) short A2[192*8];      // [Wf0,Wf1,bias,0..]
  __shared__ __align__(16) short hl[64*64];      // swizzled h bf16
  __shared__ __align__(16) float sc[64*8*2];
  __shared__ __align__(16) float bhn[64];

  const int tid = threadIdx.x;
  const int b0  = blockIdx.x*64;

  for (int idx = tid; idx < 192*64; idx += 256){
    int g = idx>>6, k = idx&63;
    Wlds[g*64 + (k ^ ((g&7)<<3))] = f2b(Whh[idx]);
  }
  for (int g = tid; g < 192; g += 256){
    A2[g*8+0] = f2b(Wih[2*g]);
    A2[g*8+1] = f2b(Wih[2*g+1]);
    float bb = bih[g] + (g < 128 ? bhh[g] : 0.0f);
    A2[g*8+2] = f2b(bb);
    A2[g*8+3]=0; A2[g*8+4]=0; A2[g*8+5]=0; A2[g*8+6]=0; A2[g*8+7]=0;
  }
  if (tid < 64) bhn[tid] = bhh[128+tid];
  for (int idx = tid; idx < 512; idx += 256){
    int s = idx>>3, t = idx&7, p = 7-t;
    const int* wr = walks + (long)(b0+s)*LLEN;
    int wp = wr[p]; int u = 7;
    #pragma unroll
    for (int j=7;j>=0;--j) if (wr[j]==wp) u = j;
    float si, ci;
    __sincosf((float)u * 0.7853981633974483f, &si, &ci);
    sc[idx*2] = si; sc[idx*2+1] = ci;
  }
  __syncthreads();

  const int lane = tid & 63;
  const int wv   = tid >> 6;
  const int c    = lane & 15;
  const int a    = lane >> 4;
  const int s    = wv*16 + c;
  const int sg   = b0 + s;

  float hreg[4][4];
  short4v z4 = {0,0,0,0};
  #pragma unroll
  for (int q=0;q<4;++q){
    #pragma unroll
    for (int r=0;r<4;++r) hreg[q][r] = 0.0f;
    int i0 = q*16 + 4*a;
    *(short4v*)&hl[s*64 + (i0 ^ ((s&7)<<3))] = z4;
  }

  for (int ss=0; ss<8; ++ss){
    const int t = dir ? 7-ss : ss;
    asm volatile("s_waitcnt lgkmcnt(0)" ::: "memory");
    bf16x8 bh0 = *(const bf16x8*)&hl[s*64 + ((a*8)      ^ ((s&7)<<3))];
    bf16x8 bh1 = *(const bf16x8*)&hl[s*64 + ((32 + a*8) ^ ((s&7)<<3))];
    bf16x8 b2 = {0,0,0,0,0,0,0,0};
    if (a == 0){
      b2[0] = f2b(sc[(s*8+t)*2]);
      b2[1] = f2b(sc[(s*8+t)*2+1]);
      b2[2] = (short)0x3F80;   // 1.0 bf16
    }
    f32x4 acc1[12]; f32x4 acc2[4];
    #pragma unroll
    for (int T=0;T<12;++T){ acc1[T].x=0;acc1[T].y=0;acc1[T].z=0;acc1[T].w=0; }
    #pragma unroll
    for (int T=0;T<4;++T){ acc2[T].x=0;acc2[T].y=0;acc2[T].z=0;acc2[T].w=0; }

    #pragma unroll
    for (int T=0;T<12;++T){
      int g = 16*T + c;
      bf16x8 a0 = *(const bf16x8*)&Wlds[g*64 + ((a*8)      ^ ((g&7)<<3))];
      bf16x8 a1 = *(const bf16x8*)&Wlds[g*64 + ((32 + a*8) ^ ((g&7)<<3))];
      acc1[T] = __builtin_amdgcn_mfma_f32_16x16x32_bf16(a0, bh0, acc1[T], 0,0,0);
      acc1[T] = __builtin_amdgcn_mfma_f32_16x16x32_bf16(a1, bh1, acc1[T], 0,0,0);
      bf16x8 a2 = *(const bf16x8*)&A2[g*8];
      if (T < 8) acc1[T]   = __builtin_amdgcn_mfma_f32_16x16x32_bf16(a2, b2, acc1[T],   0,0,0);
      else       acc2[T-8] = __builtin_amdgcn_mfma_f32_16x16x32_bf16(a2, b2, acc2[T-8], 0,0,0);
    }

    #pragma unroll
    for (int q=0;q<4;++q){
      int i0 = q*16 + 4*a;
      f32x4 bv = *(const f32x4*)&bhn[i0];
      short4v pack;
      #pragma unroll
      for (int r=0;r<4;++r){
        float rr = sigm(acc1[q][r]);
        float zz = sigm(acc1[4+q][r]);
        float hn = acc1[8+q][r] + bv[r];
        float xn = acc2[q][r];
        float nn = tanh_(xn + rr*hn);
        float hv = (1.0f-zz)*nn + zz*hreg[q][r];
        hreg[q][r] = hv;
        pack[r] = f2b(hv);
      }
      *(short4v*)&hl[s*64 + (i0 ^ ((s&7)<<3))] = pack;
      int kb = 4*q + a;
      *(short4v*)(yout + ((long)(t*16+kb)*BB + sg)*4) = pack;
    }
  }

  #pragma unroll
  for (int q=0;q<4;++q){
    int i0 = q*16 + 4*a;
    short4v pk;
    #pragma unroll
    for (int r=0;r<4;++r) pk[r] = f2b(hreg[q][r]);
    *(short4v*)(hfb + ((long)dir*BB + sg)*64 + i0) = pk;
  }
}

// ---------------- final GRU: K = 64(h,U) + 128(y,Wy) + 32(deg+bias) ----------------
__global__ __launch_bounds__(256,1) void k_final(
    const int* __restrict__ walks, const float* __restrict__ degn,
    const float* __restrict__ A,
    const float* __restrict__ W, const float* __restrict__ U,
    const float* __restrict__ bhh,
    const short* __restrict__ yf, const short* __restrict__ yb,
    const short* __restrict__ hfb,
    float* __restrict__ out)
{
  __shared__ __align__(16) short Ulds[192*64];
  __shared__ __align__(16) short Wy[192*128];
  __shared__ __align__(16) short A5[192*8];     // [Wdeg, bias_rz, 0..]
  __shared__ __align__(16) short hl[64*64];
  __shared__ __align__(16) int   node[64*8];
  __shared__ __align__(16) float degl[64*8];
  __shared__ __align__(16) float bhn[64];

  const int tid = threadIdx.x;
  const int b0  = blockIdx.x*64;

  for (int idx = tid; idx < 192*64; idx += 256){
    int g = idx>>6, k = idx&63;
    Ulds[g*64 + (k ^ ((g&7)<<3))] = f2b(U[idx]);
  }
  for (int idx = tid; idx < 192*128; idx += 256){
    int g = idx>>7, k2 = idx&127;
    Wy[g*128 + (k2 ^ ((g&7)<<3))] = f2b(W[(long)g*DD + 64 + k2]);
  }
  for (int g = tid; g < 192; g += 256){
    A5[g*8+0] = f2b(W[(long)g*DD + 192]);
    A5[g*8+1] = (g < 128) ? f2b(bhh[g]) : (short)0;
    A5[g*8+2]=0; A5[g*8+3]=0; A5[g*8+4]=0; A5[g*8+5]=0; A5[g*8+6]=0; A5[g*8+7]=0;
  }
  if (tid < 64) bhn[tid] = bhh[128+tid];
  for (int idx = tid; idx < 512; idx += 256){
    int s = idx>>3, t = idx&7;
    int nd = walks[(long)(b0+s)*LLEN + 7-t];
    node[idx] = nd;
    degl[idx] = degn[nd];
  }
  __syncthreads();

  const int lane = tid & 63;
  const int wv   = tid >> 6;
  const int c    = lane & 15;
  const int a    = lane >> 4;
  const int s    = wv*16 + c;
  const int sg   = b0 + s;

  float hreg[4][4];
  #pragma unroll
  for (int q=0;q<4;++q){
    int i0 = q*16 + 4*a;
    short4v hf4 = *(const short4v*)(hfb + (long)sg*64 + i0);
    short4v hb4 = *(const short4v*)(hfb + ((long)BB + sg)*64 + i0);
    short4v pk;
    #pragma unroll
    for (int r=0;r<4;++r){
      float hv = 0.5f*(b2f(hf4[r]) + b2f(hb4[r]));
      hreg[q][r] = hv;
      pk[r] = f2b(hv);
    }
    *(short4v*)&hl[s*64 + (i0 ^ ((s&7)<<3))] = pk;
  }

  auto ldy = [&](const short* Y, int t, int kh, bf16x8& dst){
    int ky0 = kh*32 + a*8;
    int kb  = ky0 >> 2;
    long base = ((long)(t*16 + kb)*BB + sg)*4;
    short4v lo = *(const short4v*)(Y + base);
    short4v hi = *(const short4v*)(Y + base + (long)BB*4);
    dst[0]=lo[0]; dst[1]=lo[1]; dst[2]=lo[2]; dst[3]=lo[3];
    dst[4]=hi[0]; dst[5]=hi[1]; dst[6]=hi[2]; dst[7]=hi[3];
  };

  bf16x8 yfc[2], ybc[2];
  ldy(yf, 0, 0, yfc[0]); ldy(yf, 0, 1, yfc[1]);
  ldy(yb, 0, 0, ybc[0]); ldy(yb, 0, 1, ybc[1]);

  for (int t=0; t<8; ++t){
    bf16x8 yfn[2], ybn[2];
    if (t < 7){
      ldy(yf, t+1, 0, yfn[0]); ldy(yf, t+1, 1, yfn[1]);
      ldy(yb, t+1, 0, ybn[0]); ldy(yb, t+1, 1, ybn[1]);
    }
    // A-row gather (issued early; consumed after MFMAs)
    int nd = node[s*8 + t];
    f32x4 Ag[12];
    #pragma unroll
    for (int T=0;T<12;++T) Ag[T] = *(const f32x4*)(A + (long)nd*192 + 16*T + 4*a);

    asm volatile("s_waitcnt lgkmcnt(0)" ::: "memory");
    bf16x8 bh0 = *(const bf16x8*)&hl[s*64 + ((a*8)      ^ ((s&7)<<3))];
    bf16x8 bh1 = *(const bf16x8*)&hl[s*64 + ((32 + a*8) ^ ((s&7)<<3))];
    bf16x8 b5 = {0,0,0,0,0,0,0,0};
    if (a == 0){
      b5[0] = f2b(degl[s*8+t]);
      b5[1] = (short)0x3F80;
    }

    f32x4 acc1[12]; f32x4 acc2[4];
    #pragma unroll
    for (int T=0;T<12;++T){ acc1[T].x=0;acc1[T].y=0;acc1[T].z=0;acc1[T].w=0; }
    #pragma unroll
    for (int T=0;T<4;++T){ acc2[T].x=0;acc2[T].y=0;acc2[T].z=0;acc2[T].w=0; }

    #pragma unroll
    for (int T=0;T<12;++T){
      int g = 16*T + c;
      bf16x8 u0 = *(const bf16x8*)&Ulds[g*64 + ((a*8)      ^ ((g&7)<<3))];
      bf16x8 u1 = *(const bf16x8*)&Ulds[g*64 + ((32 + a*8) ^ ((g&7)<<3))];
      acc1[T] = __builtin_amdgcn_mfma_f32_16x16x32_bf16(u0, bh0, acc1[T], 0,0,0);
      acc1[T] = __builtin_amdgcn_mfma_f32_16x16x32_bf16(u1, bh1, acc1[T], 0,0,0);
      bf16x8 w0 = *(const bf16x8*)&Wy[g*128 + ((a*8)       ^ ((g&7)<<3))];
      bf16x8 w1 = *(const bf16x8*)&Wy[g*128 + ((32 + a*8)  ^ ((g&7)<<3))];
      bf16x8 w2 = *(const bf16x8*)&Wy[g*128 + ((64 + a*8)  ^ ((g&7)<<3))];
      bf16x8 w3 = *(const bf16x8*)&Wy[g*128 + ((96 + a*8)  ^ ((g&7)<<3))];
      bf16x8 a5 = *(const bf16x8*)&A5[g*8];
      if (T < 8){
        acc1[T] = __builtin_amdgcn_mfma_f32_16x16x32_bf16(w0, yfc[0], acc1[T], 0,0,0);
        acc1[T] = __builtin_amdgcn_mfma_f32_16x16x32_bf16(w1, yfc[1], acc1[T], 0,0,0);
        acc1[T] = __builtin_amdgcn_mfma_f32_16x16x32_bf16(w2, ybc[0], acc1[T], 0,0,0);
        acc1[T] = __builtin_amdgcn_mfma_f32_16x16x32_bf16(w3, ybc[1], acc1[T], 0,0,0);
        acc1[T] = __builtin_amdgcn_mfma_f32_16x16x32_bf16(a5, b5,     acc1[T], 0,0,0);
      } else {
        acc2[T-8] = __builtin_amdgcn_mfma_f32_16x16x32_bf16(w0, yfc[0], acc2[T-8], 0,0,0);
        acc2[T-8] = __builtin_amdgcn_mfma_f32_16x16x32_bf16(w1, yfc[1], acc2[T-8], 0,0,0);
        acc2[T-8] = __builtin_amdgcn_mfma_f32_16x16x32_bf16(w2, ybc[0], acc2[T-8], 0,0,0);
        acc2[T-8] = __builtin_amdgcn_mfma_f32_16x16x32_bf16(w3, ybc[1], acc2[T-8], 0,0,0);
        acc2[T-8] = __builtin_amdgcn_mfma_f32_16x16x32_bf16(a5, b5,     acc2[T-8], 0,0,0);
      }
    }

    #pragma unroll
    for (int q=0;q<4;++q){
      int i0 = q*16 + 4*a;
      f32x4 bv = *(const f32x4*)&bhn[i0];
      short4v pack;
      #pragma unroll
      for (int r=0;r<4;++r){
        float rr = sigm(acc1[q][r]   + Ag[q][r]);
        float zz = sigm(acc1[4+q][r] + Ag[4+q][r]);
        float hn = acc1[8+q][r] + bv[r];
        float xn = acc2[q][r]   + Ag[8+q][r];
        float nn = tanh_(xn + rr*hn);
        float hv = (1.0f-zz)*nn + zz*hreg[q][r];
        hreg[q][r] = hv;
        pack[r] = f2b(hv);
      }
      *(short4v*)&hl[s*64 + (i0 ^ ((s&7)<<3))] = pack;
    }

    if (t < 7){
      yfc[0]=yfn[0]; yfc[1]=yfn[1];
      ybc[0]=ybn[0]; ybc[1]=ybn[1];
    }
  }

  #pragma unroll
  for (int q=0;q<4;++q){
    int i0 = q*16 + 4*a;
    f32x4 o;
    #pragma unroll
    for (int r=0;r<4;++r) o[r] = hreg[q][r];
    *(f32x4*)(out + (long)sg*64 + i0) = o;
  }
}

extern "C" void kernel_launch(void* const* d_in, const int* in_sizes, int n_in,
                              void* d_out, int out_size, void* d_ws, size_t ws_size,
                              hipStream_t stream) {
  const float* h     = (const float*)d_in[0];
  const int*   walks = (const int*)d_in[1];
  const int*   indeg = (const int*)d_in[2];
  const float* Wf    = (const float*)d_in[3];
  const float* Uf    = (const float*)d_in[4];
  const float* bif   = (const float*)d_in[5];
  const float* bhf   = (const float*)d_in[6];
  const float* Wb    = (const float*)d_in[7];
  const float* Ub    = (const float*)d_in[8];
  const float* bib   = (const float*)d_in[9];
  const float* bhb   = (const float*)d_in[10];
  const float* W     = (const float*)d_in[11];
  const float* U     = (const float*)d_in[12];
  const float* bi    = (const float*)d_in[13];
  const float* bh    = (const float*)d_in[14];
  float* out = (float*)d_out;

  char* ws = (char*)d_ws;
  int*   dmax = (int*)(ws + OFF_DMAX);
  float* degn = (float*)(ws + OFF_DEGN);
  float* A    = (float*)(ws + OFF_A);
  short* yfw  = (short*)(ws + OFF_YF);
  short* ybw  = (short*)(ws + OFF_YB);
  short* hfb  = (short*)(ws + OFF_HFB);

  k_zero<<<1, 64, 0, stream>>>(dmax);
  k_degmax<<<(SS*NN*LLEN + 255)/256, 256, 0, stream>>>(walks, indeg, dmax);
  k_degn<<<(NN + 255)/256, 256, 0, stream>>>(indeg, dmax, degn);
  k_A<<<(NN + 31)/32, 192, 0, stream>>>(h, W, bi, A);
  k_fb<<<dim3(BB/64, 2), 256, 0, stream>>>(walks,
                                           Wf, Uf, bif, bhf,
                                           Wb, Ub, bib, bhb,
                                           yfw, ybw, hfb);
  k_final<<<BB/64, 256, 0, stream>>>(walks, degn, A, W, U, bh,
                                     yfw, ybw, hfb, out);
}